// Round 4
// baseline (656.779 us; speedup 1.0000x reference)
//
#include <hip/hip_runtime.h>

// Problem constants: B=1, N=256, C=128, H=4, D=32
#define N 256
#define C 128
#define H 4
#define D 32
#define LN_EPS 1e-5f
#define INFB 1e9f
#define SCALE 0.17677669529663687f  // 1/sqrt(32)

typedef __bf16 bf16x8 __attribute__((ext_vector_type(8)));
typedef __bf16 bf16x2 __attribute__((ext_vector_type(2)));
typedef float floatx4 __attribute__((ext_vector_type(4)));

__device__ __forceinline__ floatx4 mfma16(bf16x8 a, bf16x8 b, floatx4 c) {
    return __builtin_amdgcn_mfma_f32_16x16x32_bf16(a, b, c, 0, 0, 0);
}

// ---------------------------------------------------------------------------
// K0: weight transpose+cvt. wTg[mat][n][c] = (bf16) w_mat[c][n].
// B-fragments for the proj GEMM then read 8 contiguous bf16 per lane.
// ---------------------------------------------------------------------------
__global__ __launch_bounds__(256) void wt_kernel(
    const float* __restrict__ wq, const float* __restrict__ wk,
    const float* __restrict__ wv, const float* __restrict__ wg,
    __bf16* __restrict__ wTg)
{
    const int mat = blockIdx.x >> 3, seg = blockIdx.x & 7;
    const float* __restrict__ ws_ = (mat == 0) ? wq : (mat == 1) ? wk
                                  : (mat == 2) ? wv : wg;
    #pragma unroll
    for (int rep = 0; rep < 8; ++rep) {
        const int idx = seg * 2048 + rep * 256 + threadIdx.x;
        const int n = idx >> 7, c = idx & 127;
        wTg[mat * 16384 + n * 128 + c] = (__bf16)ws_[c * 128 + n];
    }
}

// ---------------------------------------------------------------------------
// K1: transpose + LayerNorm -> xn bf16, plus tri-bias.
// xn row r = a*256+b holds LN(x[b,a,:]) = x_t[a,b,:]  (bf16, 128 ch).
// tbj[h][a][b] = xn_row(a,b) . w_bias[h]   (= tb[h][j=a][k=b], fp32).
// One wave per row (64 lanes x 2 channels).  (verified orientation: R3 passed)
// ---------------------------------------------------------------------------
__global__ __launch_bounds__(256) void ln_kernel(
    const float* __restrict__ x, const float* __restrict__ lnw,
    const float* __restrict__ lnb, const float* __restrict__ wbias,
    __bf16* __restrict__ xn, float* __restrict__ tbj)
{
    const int t = threadIdx.x;
    const int wv = t >> 6, lane = t & 63;
    const int r = blockIdx.x * 4 + wv;
    const int a = r >> 8, b = r & 255;

    const float2 v = *(const float2*)&x[((size_t)b * N + a) * C + lane * 2];
    float s  = v.x + v.y;
    float ss = v.x * v.x + v.y * v.y;
    #pragma unroll
    for (int o = 32; o; o >>= 1) {
        s  += __shfl_xor(s,  o);
        ss += __shfl_xor(ss, o);
    }
    const float mu  = s * (1.0f / 128.0f);
    const float var = ss * (1.0f / 128.0f) - mu * mu;
    const float rs  = rsqrtf(var + LN_EPS);

    const float2 lw = *(const float2*)&lnw[lane * 2];
    const float2 lb = *(const float2*)&lnb[lane * 2];
    const float y0 = (v.x - mu) * rs * lw.x + lb.x;
    const float y1 = (v.y - mu) * rs * lw.y + lb.y;

    bf16x2 xo; xo[0] = (__bf16)y0; xo[1] = (__bf16)y1;
    *(bf16x2*)&xn[(size_t)r * C + lane * 2] = xo;

    #pragma unroll
    for (int hh = 0; hh < H; ++hh) {
        const float2 wb2 = *(const float2*)&wbias[hh * C + lane * 2];
        float tv = y0 * wb2.x + y1 * wb2.y;
        #pragma unroll
        for (int o = 32; o; o >>= 1) tv += __shfl_xor(tv, o);
        if (lane == 0) tbj[hh * (N * N) + a * N + b] = tv;
    }
}

// ---------------------------------------------------------------------------
// K2: projection GEMM  [65536 x 128] x [128 x 128] for each of Q,K,V,G.
// grid (512 m-tiles, 4 mats), 4 waves in a 2x2 tile grid, 64x64 per wave.
// No LDS, no barriers: A-frags from xn (global, L1-reused), B-frags from
// wTg (global, L2-resident). Outputs bf16:
//   Q,K,G: [(i*4+h)*256 + row][32]   (Q pre-scaled by 1/sqrt(D))
//   V:     [(i*4+h)*32 + d][256]     (transposed for PV B-fragments)
// ---------------------------------------------------------------------------
__global__ __launch_bounds__(256, 3) void proj_kernel(
    const __bf16* __restrict__ xn, const __bf16* __restrict__ wTg,
    __bf16* __restrict__ qbuf, __bf16* __restrict__ kbuf,
    __bf16* __restrict__ vtbuf, __bf16* __restrict__ gbuf)
{
    const int mat = blockIdx.y;
    const int t = threadIdx.x, w = t >> 6, lane = t & 63;
    const int ln16 = lane & 15, quad = lane >> 4;
    const int wr = w >> 1, wc = w & 1;
    const int m_base = blockIdx.x * 128 + wr * 64;
    const int n_base = wc * 64;
    const __bf16* __restrict__ wT = wTg + mat * 16384;

    floatx4 Cf[4][4];
    const floatx4 z4 = {0.f, 0.f, 0.f, 0.f};
    #pragma unroll
    for (int mt = 0; mt < 4; ++mt)
        #pragma unroll
        for (int nt = 0; nt < 4; ++nt) Cf[mt][nt] = z4;

    #pragma unroll
    for (int ks = 0; ks < 4; ++ks) {
        bf16x8 Af[4], Bf[4];
        #pragma unroll
        for (int mt = 0; mt < 4; ++mt)
            Af[mt] = *(const bf16x8*)&xn[(size_t)(m_base + mt*16 + ln16) * 128 + ks*32 + quad*8];
        #pragma unroll
        for (int nt = 0; nt < 4; ++nt)
            Bf[nt] = *(const bf16x8*)&wT[(n_base + nt*16 + ln16) * 128 + ks*32 + quad*8];
        #pragma unroll
        for (int mt = 0; mt < 4; ++mt)
            #pragma unroll
            for (int nt = 0; nt < 4; ++nt)
                Cf[mt][nt] = mfma16(Af[mt], Bf[nt], Cf[mt][nt]);
    }

    const float scl = (mat == 0) ? SCALE : 1.0f;
    #pragma unroll
    for (int mt = 0; mt < 4; ++mt)
        #pragma unroll
        for (int nt = 0; nt < 4; ++nt)
            #pragma unroll
            for (int r = 0; r < 4; ++r) {
                const int m = m_base + mt*16 + quad*4 + r;
                const int n = n_base + nt*16 + ln16;
                const int i = m >> 8, jk = m & 255;
                const int hh = n >> 5, d = n & 31;
                const float vv = Cf[mt][nt][r] * scl;
                if (mat == 2)
                    vtbuf[(((size_t)i*4 + hh)*32 + d)*256 + jk] = (__bf16)vv;
                else {
                    __bf16* dst = (mat == 0) ? qbuf : (mat == 1) ? kbuf : gbuf;
                    dst[(((size_t)i*4 + hh)*256 + jk)*32 + d] = (__bf16)vv;
                }
            }
}

// ---------------------------------------------------------------------------
// K3: MFMA attention, one (i,h) per block, 4 waves; wave w owns j in
// [w*64, w*64+64), processed as 4 tiles of 16 queries. Full-row softmax
// (all 256 scores live in 16 C-frags = 64 VGPRs). Q/K/V/G from global
// bf16 buffers (L1/L2); P round-trips through wave-private LDS (no barrier).
// ---------------------------------------------------------------------------
__global__ __launch_bounds__(256, 3) void attn_kernel(
    const float* __restrict__ tbj, const float* __restrict__ mask,
    const float* __restrict__ bg,
    const __bf16* __restrict__ qbuf, const __bf16* __restrict__ kbuf,
    const __bf16* __restrict__ vtbuf, const __bf16* __restrict__ gbuf,
    float* __restrict__ og)
{
    const int bid = blockIdx.x;
    const int i = bid & 255, h = bid >> 8;   // h-major: consecutive blocks share tbh
    const int t = threadIdx.x, w = t >> 6, lane = t & 63;
    const int ln16 = lane & 15, quad = lane >> 4;

    __shared__ float mb[256];
    __shared__ __align__(16) __bf16 Pw[4][16 * 264];

    mb[t] = INFB * (mask[(size_t)t * N + i] - 1.0f);
    __syncthreads();

    const size_t hb = (size_t)i * 4 + h;
    const __bf16* __restrict__ qb = qbuf + hb * 8192;
    const __bf16* __restrict__ kb = kbuf + hb * 8192;
    const __bf16* __restrict__ vt = vtbuf + hb * 8192;
    const __bf16* __restrict__ gb = gbuf + hb * 8192;
    const float* __restrict__ tbh = tbj + h * (N * N);
    const float bg0 = bg[h*32 + ln16], bg1 = bg[h*32 + 16 + ln16];

    float mbv[16];
    #pragma unroll
    for (int kt = 0; kt < 16; ++kt) mbv[kt] = mb[kt*16 + ln16];

    __bf16* __restrict__ Pww = &Pw[w][0];
    const floatx4 z4 = {0.f, 0.f, 0.f, 0.f};

    #pragma unroll 1
    for (int jt = 0; jt < 4; ++jt) {
        const int jrow0 = w*64 + jt*16;
        const bf16x8 Qf = *(const bf16x8*)&qb[(jrow0 + ln16)*32 + quad*8];

        // ---- scores: 16 MFMAs over all 256 keys ----
        floatx4 S[16];
        #pragma unroll
        for (int kt = 0; kt < 16; ++kt) {
            const bf16x8 Kf = *(const bf16x8*)&kb[(kt*16 + ln16)*32 + quad*8];
            S[kt] = mfma16(Qf, Kf, z4);
        }

        // ---- bias: mask + tri-bias (tb coalesced over ln16) ----
        #pragma unroll 1
        for (int kg = 0; kg < 4; ++kg) {
            float tbv[16];
            #pragma unroll
            for (int kk = 0; kk < 4; ++kk)
                #pragma unroll
                for (int r = 0; r < 4; ++r)
                    tbv[kk*4+r] = tbh[(size_t)(jrow0 + quad*4 + r) * N + (kg*4+kk)*16 + ln16];
            #pragma unroll
            for (int kk = 0; kk < 4; ++kk)
                #pragma unroll
                for (int r = 0; r < 4; ++r)
                    S[kg*4+kk][r] += mbv[kg*4+kk] + tbv[kk*4+r];
        }

        // ---- full-row softmax (rows = quad*4+r; 16-lane shfl reduce) ----
        float mrow[4], l[4];
        #pragma unroll
        for (int r = 0; r < 4; ++r) {
            float mx = S[0][r];
            #pragma unroll
            for (int kt = 1; kt < 16; ++kt) mx = fmaxf(mx, S[kt][r]);
            #pragma unroll
            for (int off = 1; off < 16; off <<= 1) mx = fmaxf(mx, __shfl_xor(mx, off));
            mrow[r] = mx; l[r] = 0.f;
        }
        #pragma unroll
        for (int kt = 0; kt < 16; ++kt)
            #pragma unroll
            for (int r = 0; r < 4; ++r) {
                const float p = __expf(S[kt][r] - mrow[r]);
                S[kt][r] = p; l[r] += p;
            }
        #pragma unroll
        for (int r = 0; r < 4; ++r)
            #pragma unroll
            for (int off = 1; off < 16; off <<= 1) l[r] += __shfl_xor(l[r], off);

        // ---- P -> LDS (C-layout scatter), then PV MFMAs (A-layout reads) ----
        #pragma unroll
        for (int kt = 0; kt < 16; ++kt)
            #pragma unroll
            for (int r = 0; r < 4; ++r)
                Pww[(quad*4 + r)*264 + kt*16 + ln16] = (__bf16)S[kt][r];

        floatx4 O0 = z4, O1 = z4;
        #pragma unroll
        for (int ks = 0; ks < 8; ++ks) {
            const bf16x8 Af = *(const bf16x8*)&Pww[ln16*264 + ks*32 + quad*8];
            const bf16x8 V0 = *(const bf16x8*)&vt[(size_t)ln16*256 + ks*32 + quad*8];
            const bf16x8 V1 = *(const bf16x8*)&vt[(size_t)(16 + ln16)*256 + ks*32 + quad*8];
            O0 = mfma16(Af, V0, O0);
            O1 = mfma16(Af, V1, O1);
        }

        // ---- normalize, gate, store ----
        #pragma unroll
        for (int r = 0; r < 4; ++r) {
            const float inv = 1.0f / l[r];
            const int jrow = jrow0 + quad*4 + r;
            const float g0 = (float)gb[jrow*32 + ln16];
            const float g1 = (float)gb[jrow*32 + 16 + ln16];
            const float gate0 = 1.0f / (1.0f + __expf(-(g0 + bg0)));
            const float gate1 = 1.0f / (1.0f + __expf(-(g1 + bg1)));
            float* __restrict__ op = og + ((size_t)jrow * N + i) * (H*D) + h * D;
            op[ln16]      = O0[r] * inv * gate0;
            op[16 + ln16] = O1[r] * inv * gate1;
        }
    }
}

// ---------------------------------------------------------------------------
// K4: output projection out[row, c] = sum_k og[row, k] * wo[c, k] + bo[c]
// (fp32, unchanged — next round's target)
// ---------------------------------------------------------------------------
__global__ __launch_bounds__(256, 2) void outproj_kernel(
    const float* __restrict__ og, const float* __restrict__ wo,
    const float* __restrict__ bo, float* __restrict__ out)
{
    __shared__ float wol[64 * 128];  // [k][c]
    __shared__ float ogl[64 * 65];   // [r][k] padded

    const int t = threadIdx.x;
    const int row0 = blockIdx.x * 64;
    const int tc = t & 15, tr = t >> 4;
    const int c0 = tc * 8, r0 = tr * 4;

    float acc[4][8];
    #pragma unroll
    for (int rr = 0; rr < 4; ++rr)
        #pragma unroll
        for (int cc = 0; cc < 8; ++cc) acc[rr][cc] = 0.f;

    #pragma unroll 1
    for (int kh = 0; kh < 2; ++kh) {
        __syncthreads();
        #pragma unroll 1
        for (int n = 0; n < 8; ++n) {
            const int e = n * 256 + t;
            const int kq = e & 15, c = e >> 4;
            const float4 f = *(const float4*)&wo[c * 128 + kh * 64 + kq * 4];
            wol[(kq*4+0) * 128 + c] = f.x;
            wol[(kq*4+1) * 128 + c] = f.y;
            wol[(kq*4+2) * 128 + c] = f.z;
            wol[(kq*4+3) * 128 + c] = f.w;
        }
        #pragma unroll 1
        for (int n = 0; n < 4; ++n) {
            const int e = n * 256 + t;
            const int kq = e & 15, r = e >> 4;
            const float4 f = *(const float4*)&og[(size_t)(row0 + r) * 128 + kh * 64 + kq * 4];
            ogl[r * 65 + kq*4+0] = f.x;
            ogl[r * 65 + kq*4+1] = f.y;
            ogl[r * 65 + kq*4+2] = f.z;
            ogl[r * 65 + kq*4+3] = f.w;
        }
        __syncthreads();
        #pragma unroll 1
        for (int k = 0; k < 64; ++k) {
            const float4 w0 = *(const float4*)&wol[k * 128 + c0];
            const float4 w1 = *(const float4*)&wol[k * 128 + c0 + 4];
            #pragma unroll
            for (int rr = 0; rr < 4; ++rr) {
                const float ov = ogl[(r0 + rr) * 65 + k];
                acc[rr][0] += ov * w0.x; acc[rr][1] += ov * w0.y;
                acc[rr][2] += ov * w0.z; acc[rr][3] += ov * w0.w;
                acc[rr][4] += ov * w1.x; acc[rr][5] += ov * w1.y;
                acc[rr][6] += ov * w1.z; acc[rr][7] += ov * w1.w;
            }
        }
    }

    const float4 b0 = *(const float4*)&bo[c0];
    const float4 b1 = *(const float4*)&bo[c0 + 4];
    #pragma unroll
    for (int rr = 0; rr < 4; ++rr) {
        const size_t ro = (size_t)(row0 + r0 + rr) * 128 + c0;
        *(float4*)&out[ro]     = make_float4(acc[rr][0]+b0.x, acc[rr][1]+b0.y,
                                             acc[rr][2]+b0.z, acc[rr][3]+b0.w);
        *(float4*)&out[ro + 4] = make_float4(acc[rr][4]+b1.x, acc[rr][5]+b1.y,
                                             acc[rr][6]+b1.z, acc[rr][7]+b1.w);
    }
}

// ---------------------------------------------------------------------------
extern "C" void kernel_launch(void* const* d_in, const int* in_sizes, int n_in,
                              void* d_out, int out_size, void* d_ws, size_t ws_size,
                              hipStream_t stream) {
    const float* x     = (const float*)d_in[0];
    const float* mask  = (const float*)d_in[1];
    const float* lnw   = (const float*)d_in[2];
    const float* lnb   = (const float*)d_in[3];
    const float* wbias = (const float*)d_in[4];
    const float* wq    = (const float*)d_in[5];
    const float* wk    = (const float*)d_in[6];
    const float* wv    = (const float*)d_in[7];
    const float* wg    = (const float*)d_in[8];
    const float* bg    = (const float*)d_in[9];
    const float* wo    = (const float*)d_in[10];
    const float* bo    = (const float*)d_in[11];
    float* out = (float*)d_out;

    // workspace layout (bytes):
    char* wsb = (char*)d_ws;
    __bf16* xn    = (__bf16*)(wsb);              // 16.8 MB
    float*  tbj   = (float*) (wsb + 16777216);   //  1.0 MB
    __bf16* wTg   = (__bf16*)(wsb + 17825792);   //  0.13 MB
    __bf16* qbuf  = (__bf16*)(wsb + 17956864);   // 16.8 MB
    __bf16* kbuf  = (__bf16*)(wsb + 34734080);   // 16.8 MB
    __bf16* vtbuf = (__bf16*)(wsb + 51511296);   // 16.8 MB
    __bf16* gbuf  = (__bf16*)(wsb + 68288512);   // 16.8 MB
    float*  og    = (float*) (wsb + 85065728);   // 33.5 MB  (total ~118.6 MB)

    wt_kernel<<<32, 256, 0, stream>>>(wq, wk, wv, wg, wTg);
    ln_kernel<<<16384, 256, 0, stream>>>(x, lnw, lnb, wbias, xn, tbj);
    proj_kernel<<<dim3(512, 4), 256, 0, stream>>>(xn, wTg, qbuf, kbuf, vtbuf, gbuf);
    attn_kernel<<<1024, 256, 0, stream>>>(tbj, mask, bg, qbuf, kbuf, vtbuf, gbuf, og);
    outproj_kernel<<<1024, 256, 0, stream>>>(og, wo, bo, out);
}

// Round 5
// 455.317 us; speedup vs baseline: 1.4425x; 1.4425x over previous
//
#include <hip/hip_runtime.h>

// Problem constants: B=1, N=256, C=128, H=4, D=32
#define N 256
#define C 128
#define H 4
#define D 32
#define LN_EPS 1e-5f
#define INFB 1e9f
#define SCALE 0.17677669529663687f  // 1/sqrt(32)

typedef __bf16 bf16x8 __attribute__((ext_vector_type(8)));
typedef __bf16 bf16x2 __attribute__((ext_vector_type(2)));
typedef float floatx4 __attribute__((ext_vector_type(4)));

__device__ __forceinline__ floatx4 mfma16(bf16x8 a, bf16x8 b, floatx4 c) {
    return __builtin_amdgcn_mfma_f32_16x16x32_bf16(a, b, c, 0, 0, 0);
}

// ---------------------------------------------------------------------------
// K0: weight transpose+cvt. wTg[mat][n][c] = (bf16) w_mat[c][n].
// ---------------------------------------------------------------------------
__global__ __launch_bounds__(256) void wt_kernel(
    const float* __restrict__ wq, const float* __restrict__ wk,
    const float* __restrict__ wv, const float* __restrict__ wg,
    __bf16* __restrict__ wTg)
{
    const int mat = blockIdx.x >> 3, seg = blockIdx.x & 7;
    const float* __restrict__ ws_ = (mat == 0) ? wq : (mat == 1) ? wk
                                  : (mat == 2) ? wv : wg;
    #pragma unroll
    for (int rep = 0; rep < 8; ++rep) {
        const int idx = seg * 2048 + rep * 256 + threadIdx.x;
        const int n = idx >> 7, c = idx & 127;
        wTg[mat * 16384 + n * 128 + c] = (__bf16)ws_[c * 128 + n];
    }
}

// ---------------------------------------------------------------------------
// K1: transpose + LayerNorm -> xn bf16, plus tri-bias (fp32, [h][j][k]).
// xn row r = a*256+b holds LN(x[b,a,:]) = x_t[a,b,:].
// ---------------------------------------------------------------------------
__global__ __launch_bounds__(256) void ln_kernel(
    const float* __restrict__ x, const float* __restrict__ lnw,
    const float* __restrict__ lnb, const float* __restrict__ wbias,
    __bf16* __restrict__ xn, float* __restrict__ tbj)
{
    const int t = threadIdx.x;
    const int wv = t >> 6, lane = t & 63;
    const int r = blockIdx.x * 4 + wv;
    const int a = r >> 8, b = r & 255;

    const float2 v = *(const float2*)&x[((size_t)b * N + a) * C + lane * 2];
    float s  = v.x + v.y;
    float ss = v.x * v.x + v.y * v.y;
    #pragma unroll
    for (int o = 32; o; o >>= 1) {
        s  += __shfl_xor(s,  o);
        ss += __shfl_xor(ss, o);
    }
    const float mu  = s * (1.0f / 128.0f);
    const float var = ss * (1.0f / 128.0f) - mu * mu;
    const float rs  = rsqrtf(var + LN_EPS);

    const float2 lw = *(const float2*)&lnw[lane * 2];
    const float2 lb = *(const float2*)&lnb[lane * 2];
    const float y0 = (v.x - mu) * rs * lw.x + lb.x;
    const float y1 = (v.y - mu) * rs * lw.y + lb.y;

    bf16x2 xo; xo[0] = (__bf16)y0; xo[1] = (__bf16)y1;
    *(bf16x2*)&xn[(size_t)r * C + lane * 2] = xo;

    #pragma unroll
    for (int hh = 0; hh < H; ++hh) {
        const float2 wb2 = *(const float2*)&wbias[hh * C + lane * 2];
        float tv = y0 * wb2.x + y1 * wb2.y;
        #pragma unroll
        for (int o = 32; o; o >>= 1) tv += __shfl_xor(tv, o);
        if (lane == 0) tbj[hh * (N * N) + a * N + b] = tv;
    }
}

// ---------------------------------------------------------------------------
// K2: projection GEMM [65536x128]x[128x128] per mat (Q,K,V,G). 4 waves in
// 2x2 64x64 tiles. C-tiles round-trip wave-private LDS (bf16) so global
// writes are 4KB-contiguous per (head, 64-row) chunk.
// All outputs layout [i*4+h][row][32] bf16; Q pre-scaled by 1/sqrt(D).
// ---------------------------------------------------------------------------
__global__ __launch_bounds__(256, 3) void proj_kernel(
    const __bf16* __restrict__ xn, const __bf16* __restrict__ wTg,
    __bf16* __restrict__ qbuf, __bf16* __restrict__ kbuf,
    __bf16* __restrict__ vbuf, __bf16* __restrict__ gbuf)
{
    __shared__ __bf16 Cs[4][64 * 72];   // 36.9 KB, wave-private tiles

    const int mat = blockIdx.y;
    const int t = threadIdx.x, w = t >> 6, lane = t & 63;
    const int ln16 = lane & 15, quad = lane >> 4;
    const int wr = w >> 1, wc = w & 1;
    const int m_base = blockIdx.x * 128 + wr * 64;
    const int n_base = wc * 64;
    const __bf16* __restrict__ wT = wTg + mat * 16384;

    floatx4 Cf[4][4];
    const floatx4 z4 = {0.f, 0.f, 0.f, 0.f};
    #pragma unroll
    for (int mt = 0; mt < 4; ++mt)
        #pragma unroll
        for (int nt = 0; nt < 4; ++nt) Cf[mt][nt] = z4;

    #pragma unroll
    for (int ks = 0; ks < 4; ++ks) {
        bf16x8 Af[4], Bf[4];
        #pragma unroll
        for (int mt = 0; mt < 4; ++mt)
            Af[mt] = *(const bf16x8*)&xn[(size_t)(m_base + mt*16 + ln16) * 128 + ks*32 + quad*8];
        #pragma unroll
        for (int nt = 0; nt < 4; ++nt)
            Bf[nt] = *(const bf16x8*)&wT[(n_base + nt*16 + ln16) * 128 + ks*32 + quad*8];
        #pragma unroll
        for (int mt = 0; mt < 4; ++mt)
            #pragma unroll
            for (int nt = 0; nt < 4; ++nt)
                Cf[mt][nt] = mfma16(Af[mt], Bf[nt], Cf[mt][nt]);
    }

    // C -> wave-private LDS (bf16), rows m-local, cols n-local
    const float scl = (mat == 0) ? SCALE : 1.0f;
    __bf16* __restrict__ Cw = &Cs[w][0];
    #pragma unroll
    for (int mt = 0; mt < 4; ++mt)
        #pragma unroll
        for (int nt = 0; nt < 4; ++nt)
            #pragma unroll
            for (int r = 0; r < 4; ++r)
                Cw[(mt*16 + quad*4 + r) * 72 + nt*16 + ln16] =
                    (__bf16)(Cf[mt][nt][r] * scl);

    // wave-private LDS read-back (in-order DS pipe, no barrier) + 4KB writes
    __bf16* __restrict__ dst = (mat == 0) ? qbuf : (mat == 1) ? kbuf
                             : (mat == 2) ? vbuf : gbuf;
    const int m = m_base + lane;
    const int i = m >> 8, jk = m & 255;
    #pragma unroll
    for (int hf = 0; hf < 2; ++hf) {
        const int hh = wc * 2 + hf;
        __bf16* __restrict__ drow = dst + (((size_t)i*4 + hh)*256 + jk)*32;
        #pragma unroll
        for (int u = 0; u < 4; ++u)
            *(bf16x8*)&drow[u*8] = *(const bf16x8*)&Cw[lane*72 + hf*32 + u*8];
    }
}

// ---------------------------------------------------------------------------
// K3: MFMA attention, one (i,h) per block, 4 waves; wave w owns 64 queries.
// K staged to LDS (pad-40), V transposed into LDS (stride 264) ONCE per
// block; Q/G read once from global (coalesced). Full-row softmax in C-frags.
// og written as the block's contiguous 32KB chunk: og[h][i][j][32] fp32.
// ---------------------------------------------------------------------------
__global__ __launch_bounds__(256, 2) void attn_kernel(
    const float* __restrict__ tbj, const float* __restrict__ mask,
    const float* __restrict__ bg,
    const __bf16* __restrict__ qbuf, const __bf16* __restrict__ kbuf,
    const __bf16* __restrict__ vbuf, const __bf16* __restrict__ gbuf,
    float* __restrict__ og)
{
    const int bid = blockIdx.x;
    const int i = bid & 255, h = bid >> 8;   // h-major: blocks share tbh slice
    const int t = threadIdx.x, w = t >> 6, lane = t & 63;
    const int ln16 = lane & 15, quad = lane >> 4;

    __shared__ __align__(16) __bf16 Ks[256 * 40];      // 20480 B
    __shared__ __align__(16) __bf16 VT[32 * 264];      // 16896 B
    __shared__ __align__(16) __bf16 Pw[4][16 * 264];   // 33792 B
    __shared__ float mb[256];                          //  1024 B

    const size_t hb = (size_t)i * 4 + h;
    const __bf16* __restrict__ qb = qbuf + hb * 8192;
    const __bf16* __restrict__ kb = kbuf + hb * 8192;
    const __bf16* __restrict__ vb = vbuf + hb * 8192;
    const __bf16* __restrict__ gb = gbuf + hb * 8192;

    // one-time staging: K rows + V transpose + mask bias
    #pragma unroll
    for (int u = 0; u < 4; ++u)
        *(bf16x8*)&Ks[t * 40 + u * 8] = *(const bf16x8*)&kb[t * 32 + u * 8];
    #pragma unroll
    for (int u = 0; u < 4; ++u) {
        const bf16x8 vv = *(const bf16x8*)&vb[t * 32 + u * 8];
        #pragma unroll
        for (int e = 0; e < 8; ++e) VT[(u*8 + e) * 264 + t] = vv[e];
    }
    mb[t] = INFB * (mask[(size_t)t * N + i] - 1.0f);
    __syncthreads();

    const float* __restrict__ tbh = tbj + h * (N * N);
    const float bg0 = bg[h*32 + ln16], bg1 = bg[h*32 + 16 + ln16];

    float mbv[16];
    #pragma unroll
    for (int kt = 0; kt < 16; ++kt) mbv[kt] = mb[kt*16 + ln16];

    __bf16* __restrict__ Pww = &Pw[w][0];
    const floatx4 z4 = {0.f, 0.f, 0.f, 0.f};
    float* __restrict__ ogb = og + (((size_t)h * 256 + i) * 256) * 32;

    #pragma unroll 1
    for (int jt = 0; jt < 4; ++jt) {
        const int jrow0 = w*64 + jt*16;
        const bf16x8 Qf = *(const bf16x8*)&qb[(jrow0 + ln16)*32 + quad*8];

        // ---- scores: 16 MFMAs over all 256 keys (K from LDS) ----
        floatx4 S[16];
        #pragma unroll
        for (int kt = 0; kt < 16; ++kt) {
            const bf16x8 Kf = *(const bf16x8*)&Ks[(kt*16 + ln16)*40 + quad*8];
            S[kt] = mfma16(Qf, Kf, z4);
        }

        // ---- bias: mask + tri-bias ----
        #pragma unroll 1
        for (int kg = 0; kg < 4; ++kg) {
            float tbv[16];
            #pragma unroll
            for (int kk = 0; kk < 4; ++kk)
                #pragma unroll
                for (int r = 0; r < 4; ++r)
                    tbv[kk*4+r] = tbh[(size_t)(jrow0 + quad*4 + r) * N + (kg*4+kk)*16 + ln16];
            #pragma unroll
            for (int kk = 0; kk < 4; ++kk)
                #pragma unroll
                for (int r = 0; r < 4; ++r)
                    S[kg*4+kk][r] += mbv[kg*4+kk] + tbv[kk*4+r];
        }

        // ---- full-row softmax (16-lane shfl reduce) ----
        float mrow[4], l[4];
        #pragma unroll
        for (int r = 0; r < 4; ++r) {
            float mx = S[0][r];
            #pragma unroll
            for (int kt = 1; kt < 16; ++kt) mx = fmaxf(mx, S[kt][r]);
            #pragma unroll
            for (int off = 1; off < 16; off <<= 1) mx = fmaxf(mx, __shfl_xor(mx, off));
            mrow[r] = mx; l[r] = 0.f;
        }
        #pragma unroll
        for (int kt = 0; kt < 16; ++kt)
            #pragma unroll
            for (int r = 0; r < 4; ++r) {
                const float p = __expf(S[kt][r] - mrow[r]);
                S[kt][r] = p; l[r] += p;
            }
        #pragma unroll
        for (int r = 0; r < 4; ++r)
            #pragma unroll
            for (int off = 1; off < 16; off <<= 1) l[r] += __shfl_xor(l[r], off);

        // ---- P -> LDS, then PV MFMAs (A from LDS, B from VT LDS) ----
        #pragma unroll
        for (int kt = 0; kt < 16; ++kt)
            #pragma unroll
            for (int r = 0; r < 4; ++r)
                Pww[(quad*4 + r)*264 + kt*16 + ln16] = (__bf16)S[kt][r];

        floatx4 O0 = z4, O1 = z4;
        #pragma unroll
        for (int ks = 0; ks < 8; ++ks) {
            const bf16x8 Af = *(const bf16x8*)&Pww[ln16*264 + ks*32 + quad*8];
            const bf16x8 V0 = *(const bf16x8*)&VT[ln16*264 + ks*32 + quad*8];
            const bf16x8 V1 = *(const bf16x8*)&VT[(16 + ln16)*264 + ks*32 + quad*8];
            O0 = mfma16(Af, V0, O0);
            O1 = mfma16(Af, V1, O1);
        }

        // ---- normalize, gate, store (contiguous block-private og chunk) ----
        #pragma unroll
        for (int r = 0; r < 4; ++r) {
            const float inv = 1.0f / l[r];
            const int jrow = jrow0 + quad*4 + r;
            const float g0 = (float)gb[jrow*32 + ln16];
            const float g1 = (float)gb[jrow*32 + 16 + ln16];
            const float gate0 = 1.0f / (1.0f + __expf(-(g0 + bg0)));
            const float gate1 = 1.0f / (1.0f + __expf(-(g1 + bg1)));
            float* __restrict__ op = ogb + jrow * 32;
            op[ln16]      = O0[r] * inv * gate0;
            op[16 + ln16] = O1[r] * inv * gate1;
        }
    }
}

// ---------------------------------------------------------------------------
// K4: output projection. Block = (i, 64 j's): og reads contiguous 8KB runs,
// out rows written as full 512B lines. out[(j*256+i)*128 + c].
// ---------------------------------------------------------------------------
__global__ __launch_bounds__(256, 2) void outproj_kernel(
    const float* __restrict__ og, const float* __restrict__ wo,
    const float* __restrict__ bo, float* __restrict__ out)
{
    __shared__ float wol[64 * 128];  // [k][c]
    __shared__ float ogl[64 * 65];   // [r][k] padded

    const int t = threadIdx.x;
    const int i  = blockIdx.x & 255;
    const int j0 = (blockIdx.x >> 8) * 64;
    const int tc = t & 15, tr = t >> 4;
    const int c0 = tc * 8, r0 = tr * 4;

    float acc[4][8];
    #pragma unroll
    for (int rr = 0; rr < 4; ++rr)
        #pragma unroll
        for (int cc = 0; cc < 8; ++cc) acc[rr][cc] = 0.f;

    #pragma unroll 1
    for (int kh = 0; kh < 2; ++kh) {
        __syncthreads();
        // stage wo[c][kh*64 + k] -> wol[k][c]
        #pragma unroll 1
        for (int n = 0; n < 8; ++n) {
            const int e = n * 256 + t;
            const int kq = e & 15, c = e >> 4;
            const float4 f = *(const float4*)&wo[c * 128 + kh * 64 + kq * 4];
            wol[(kq*4+0) * 128 + c] = f.x;
            wol[(kq*4+1) * 128 + c] = f.y;
            wol[(kq*4+2) * 128 + c] = f.z;
            wol[(kq*4+3) * 128 + c] = f.w;
        }
        // stage og[h][i][j0+r][d] -> ogl[r][k], k = h*32+d
        #pragma unroll 1
        for (int n = 0; n < 4; ++n) {
            const int e = n * 256 + t;
            const int kq = e & 15, r = e >> 4;
            const int k = kh * 64 + kq * 4;
            const int hh = k >> 5, d0 = k & 31;
            const float4 f = *(const float4*)&og[(((size_t)hh*256 + i)*256 + j0 + r)*32 + d0];
            ogl[r * 65 + kq*4+0] = f.x;
            ogl[r * 65 + kq*4+1] = f.y;
            ogl[r * 65 + kq*4+2] = f.z;
            ogl[r * 65 + kq*4+3] = f.w;
        }
        __syncthreads();
        #pragma unroll 1
        for (int k = 0; k < 64; ++k) {
            const float4 w0 = *(const float4*)&wol[k * 128 + c0];
            const float4 w1 = *(const float4*)&wol[k * 128 + c0 + 4];
            #pragma unroll
            for (int rr = 0; rr < 4; ++rr) {
                const float ov = ogl[(r0 + rr) * 65 + k];
                acc[rr][0] += ov * w0.x; acc[rr][1] += ov * w0.y;
                acc[rr][2] += ov * w0.z; acc[rr][3] += ov * w0.w;
                acc[rr][4] += ov * w1.x; acc[rr][5] += ov * w1.y;
                acc[rr][6] += ov * w1.z; acc[rr][7] += ov * w1.w;
            }
        }
    }

    const float4 b0 = *(const float4*)&bo[c0];
    const float4 b1 = *(const float4*)&bo[c0 + 4];
    #pragma unroll
    for (int rr = 0; rr < 4; ++rr) {
        const size_t ro = ((size_t)(j0 + r0 + rr) * 256 + i) * 128 + c0;
        *(float4*)&out[ro]     = make_float4(acc[rr][0]+b0.x, acc[rr][1]+b0.y,
                                             acc[rr][2]+b0.z, acc[rr][3]+b0.w);
        *(float4*)&out[ro + 4] = make_float4(acc[rr][4]+b1.x, acc[rr][5]+b1.y,
                                             acc[rr][6]+b1.z, acc[rr][7]+b1.w);
    }
}

// ---------------------------------------------------------------------------
extern "C" void kernel_launch(void* const* d_in, const int* in_sizes, int n_in,
                              void* d_out, int out_size, void* d_ws, size_t ws_size,
                              hipStream_t stream) {
    const float* x     = (const float*)d_in[0];
    const float* mask  = (const float*)d_in[1];
    const float* lnw   = (const float*)d_in[2];
    const float* lnb   = (const float*)d_in[3];
    const float* wbias = (const float*)d_in[4];
    const float* wq    = (const float*)d_in[5];
    const float* wk    = (const float*)d_in[6];
    const float* wv    = (const float*)d_in[7];
    const float* wg    = (const float*)d_in[8];
    const float* bg    = (const float*)d_in[9];
    const float* wo    = (const float*)d_in[10];
    const float* bo    = (const float*)d_in[11];
    float* out = (float*)d_out;

    char* wsb = (char*)d_ws;
    __bf16* xn    = (__bf16*)(wsb);              // 16.8 MB
    float*  tbj   = (float*) (wsb + 16777216);   //  1.0 MB
    __bf16* wTg   = (__bf16*)(wsb + 17825792);   //  0.13 MB
    __bf16* qbuf  = (__bf16*)(wsb + 17956864);   // 16.8 MB
    __bf16* kbuf  = (__bf16*)(wsb + 34734080);   // 16.8 MB
    __bf16* vbuf  = (__bf16*)(wsb + 51511296);   // 16.8 MB
    __bf16* gbuf  = (__bf16*)(wsb + 68288512);   // 16.8 MB
    float*  og    = (float*) (wsb + 85065728);   // 33.5 MB  (total ~118.6 MB)

    wt_kernel<<<32, 256, 0, stream>>>(wq, wk, wv, wg, wTg);
    ln_kernel<<<16384, 256, 0, stream>>>(x, lnw, lnb, wbias, xn, tbj);
    proj_kernel<<<dim3(512, 4), 256, 0, stream>>>(xn, wTg, qbuf, kbuf, vbuf, gbuf);
    attn_kernel<<<1024, 256, 0, stream>>>(tbj, mask, bg, qbuf, kbuf, vbuf, gbuf, og);
    outproj_kernel<<<1024, 256, 0, stream>>>(og, wo, bo, out);
}

// Round 7
// 418.335 us; speedup vs baseline: 1.5700x; 1.0884x over previous
//
#include <hip/hip_runtime.h>

// Problem constants: B=1, N=256, C=128, H=4, D=32
#define N 256
#define C 128
#define H 4
#define D 32
#define LN_EPS 1e-5f
#define INFB 1e9f
#define SCALE 0.17677669529663687f  // 1/sqrt(32)

typedef __bf16 bf16x8 __attribute__((ext_vector_type(8)));
typedef __bf16 bf16x2 __attribute__((ext_vector_type(2)));
typedef _Float16 halfx8 __attribute__((ext_vector_type(8)));
typedef float floatx4 __attribute__((ext_vector_type(4)));

__device__ __forceinline__ floatx4 mfma16(bf16x8 a, bf16x8 b, floatx4 c) {
    return __builtin_amdgcn_mfma_f32_16x16x32_bf16(a, b, c, 0, 0, 0);
}
__device__ __forceinline__ floatx4 mfma16h(halfx8 a, halfx8 b, floatx4 c) {
    return __builtin_amdgcn_mfma_f32_16x16x32_f16(a, b, c, 0, 0, 0);
}

// ---------------------------------------------------------------------------
// K0: weight prep. mats 0..3: wTg[mat][n][c] = (bf16) w[c][n] (transposed).
// mat 4: woh[c][k] = (fp16) wo[c][k] (plain convert, layout kept k-major).
// ---------------------------------------------------------------------------
__global__ __launch_bounds__(256) void wt_kernel(
    const float* __restrict__ wq, const float* __restrict__ wk,
    const float* __restrict__ wv, const float* __restrict__ wg,
    const float* __restrict__ wo, __bf16* __restrict__ wTg,
    _Float16* __restrict__ woh)
{
    const int mat = blockIdx.x >> 3, seg = blockIdx.x & 7;
    if (mat == 4) {
        #pragma unroll
        for (int rep = 0; rep < 8; ++rep) {
            const int idx = seg * 2048 + rep * 256 + threadIdx.x;
            woh[idx] = (_Float16)wo[idx];
        }
        return;
    }
    const float* __restrict__ ws_ = (mat == 0) ? wq : (mat == 1) ? wk
                                  : (mat == 2) ? wv : wg;
    #pragma unroll
    for (int rep = 0; rep < 8; ++rep) {
        const int idx = seg * 2048 + rep * 256 + threadIdx.x;
        const int n = idx >> 7, c = idx & 127;
        wTg[mat * 16384 + n * 128 + c] = (__bf16)ws_[c * 128 + n];
    }
}

// ---------------------------------------------------------------------------
// K1: transpose + LayerNorm -> xn bf16, plus tri-bias (fp32, [h][j][k]).
// xn row r = a*256+b holds LN(x[b,a,:]) = x_t[a,b,:].
// ---------------------------------------------------------------------------
__global__ __launch_bounds__(256) void ln_kernel(
    const float* __restrict__ x, const float* __restrict__ lnw,
    const float* __restrict__ lnb, const float* __restrict__ wbias,
    __bf16* __restrict__ xn, float* __restrict__ tbj)
{
    const int t = threadIdx.x;
    const int wv = t >> 6, lane = t & 63;
    const int r = blockIdx.x * 4 + wv;
    const int a = r >> 8, b = r & 255;

    const float2 v = *(const float2*)&x[((size_t)b * N + a) * C + lane * 2];
    float s  = v.x + v.y;
    float ss = v.x * v.x + v.y * v.y;
    #pragma unroll
    for (int o = 32; o; o >>= 1) {
        s  += __shfl_xor(s,  o);
        ss += __shfl_xor(ss, o);
    }
    const float mu  = s * (1.0f / 128.0f);
    const float var = ss * (1.0f / 128.0f) - mu * mu;
    const float rs  = rsqrtf(var + LN_EPS);

    const float2 lw = *(const float2*)&lnw[lane * 2];
    const float2 lb = *(const float2*)&lnb[lane * 2];
    const float y0 = (v.x - mu) * rs * lw.x + lb.x;
    const float y1 = (v.y - mu) * rs * lw.y + lb.y;

    bf16x2 xo; xo[0] = (__bf16)y0; xo[1] = (__bf16)y1;
    *(bf16x2*)&xn[(size_t)r * C + lane * 2] = xo;

    #pragma unroll
    for (int hh = 0; hh < H; ++hh) {
        const float2 wb2 = *(const float2*)&wbias[hh * C + lane * 2];
        float tv = y0 * wb2.x + y1 * wb2.y;
        #pragma unroll
        for (int o = 32; o; o >>= 1) tv += __shfl_xor(tv, o);
        if (lane == 0) tbj[hh * (N * N) + a * N + b] = tv;
    }
}

// ---------------------------------------------------------------------------
// K2: projection GEMM [65536x128]x[128x128] per mat (Q,K,V,G). 4 waves in
// 2x2 64x64 tiles; C-tiles round-trip wave-private LDS so global writes are
// 4KB-contiguous. Outputs [i*4+h][row][32] bf16; Q pre-scaled.
// ---------------------------------------------------------------------------
__global__ __launch_bounds__(256, 3) void proj_kernel(
    const __bf16* __restrict__ xn, const __bf16* __restrict__ wTg,
    __bf16* __restrict__ qbuf, __bf16* __restrict__ kbuf,
    __bf16* __restrict__ vbuf, __bf16* __restrict__ gbuf)
{
    __shared__ __bf16 Cs[4][64 * 72];

    const int mat = blockIdx.y;
    const int t = threadIdx.x, w = t >> 6, lane = t & 63;
    const int ln16 = lane & 15, quad = lane >> 4;
    const int wr = w >> 1, wc = w & 1;
    const int m_base = blockIdx.x * 128 + wr * 64;
    const int n_base = wc * 64;
    const __bf16* __restrict__ wT = wTg + mat * 16384;

    floatx4 Cf[4][4];
    const floatx4 z4 = {0.f, 0.f, 0.f, 0.f};
    #pragma unroll
    for (int mt = 0; mt < 4; ++mt)
        #pragma unroll
        for (int nt = 0; nt < 4; ++nt) Cf[mt][nt] = z4;

    #pragma unroll
    for (int ks = 0; ks < 4; ++ks) {
        bf16x8 Af[4], Bf[4];
        #pragma unroll
        for (int mt = 0; mt < 4; ++mt)
            Af[mt] = *(const bf16x8*)&xn[(size_t)(m_base + mt*16 + ln16) * 128 + ks*32 + quad*8];
        #pragma unroll
        for (int nt = 0; nt < 4; ++nt)
            Bf[nt] = *(const bf16x8*)&wT[(n_base + nt*16 + ln16) * 128 + ks*32 + quad*8];
        #pragma unroll
        for (int mt = 0; mt < 4; ++mt)
            #pragma unroll
            for (int nt = 0; nt < 4; ++nt)
                Cf[mt][nt] = mfma16(Af[mt], Bf[nt], Cf[mt][nt]);
    }

    const float scl = (mat == 0) ? SCALE : 1.0f;
    __bf16* __restrict__ Cw = &Cs[w][0];
    #pragma unroll
    for (int mt = 0; mt < 4; ++mt)
        #pragma unroll
        for (int nt = 0; nt < 4; ++nt)
            #pragma unroll
            for (int r = 0; r < 4; ++r)
                Cw[(mt*16 + quad*4 + r) * 72 + nt*16 + ln16] =
                    (__bf16)(Cf[mt][nt][r] * scl);

    __bf16* __restrict__ dst = (mat == 0) ? qbuf : (mat == 1) ? kbuf
                             : (mat == 2) ? vbuf : gbuf;
    const int m = m_base + lane;
    const int i = m >> 8, jk = m & 255;
    #pragma unroll
    for (int hf = 0; hf < 2; ++hf) {
        const int hh = wc * 2 + hf;
        __bf16* __restrict__ drow = dst + (((size_t)i*4 + hh)*256 + jk)*32;
        #pragma unroll
        for (int u = 0; u < 4; ++u)
            *(bf16x8*)&drow[u*8] = *(const bf16x8*)&Cw[lane*72 + hf*32 + u*8];
    }
}

// ---------------------------------------------------------------------------
// K3: MFMA attention, one (i,h) per block. K staged to LDS (pad-40), V
// transposed to LDS (stride 264) once; full-row softmax in C-frags; og
// written fp16 as contiguous 1KB-per-wave stores (LDS repack epilogue).
// og layout [h][i][j][32] fp16 -> block chunk = 16KB contiguous.
// ---------------------------------------------------------------------------
__global__ __launch_bounds__(256, 2) void attn_kernel(
    const float* __restrict__ tbj, const float* __restrict__ mask,
    const float* __restrict__ bg,
    const __bf16* __restrict__ qbuf, const __bf16* __restrict__ kbuf,
    const __bf16* __restrict__ vbuf, const __bf16* __restrict__ gbuf,
    _Float16* __restrict__ ogh)
{
    const int bid = blockIdx.x;
    const int i = bid & 255, h = bid >> 8;
    const int t = threadIdx.x, w = t >> 6, lane = t & 63;
    const int ln16 = lane & 15, quad = lane >> 4;

    __shared__ __align__(16) __bf16 Ks[256 * 40];      // 20480 B
    __shared__ __align__(16) __bf16 VT[32 * 264];      // 16896 B
    __shared__ __align__(16) __bf16 Pw[4][16 * 264];   // 33792 B
    __shared__ float mb[256];                          //  1024 B

    const size_t hb = (size_t)i * 4 + h;
    const __bf16* __restrict__ qb = qbuf + hb * 8192;
    const __bf16* __restrict__ kb = kbuf + hb * 8192;
    const __bf16* __restrict__ vb = vbuf + hb * 8192;
    const __bf16* __restrict__ gb = gbuf + hb * 8192;

    #pragma unroll
    for (int u = 0; u < 4; ++u)
        *(bf16x8*)&Ks[t * 40 + u * 8] = *(const bf16x8*)&kb[t * 32 + u * 8];
    #pragma unroll
    for (int u = 0; u < 4; ++u) {
        const bf16x8 vv = *(const bf16x8*)&vb[t * 32 + u * 8];
        #pragma unroll
        for (int e = 0; e < 8; ++e) VT[(u*8 + e) * 264 + t] = vv[e];
    }
    mb[t] = INFB * (mask[(size_t)t * N + i] - 1.0f);
    __syncthreads();

    const float* __restrict__ tbh = tbj + h * (N * N);
    const float bg0 = bg[h*32 + ln16], bg1 = bg[h*32 + 16 + ln16];

    float mbv[16];
    #pragma unroll
    for (int kt = 0; kt < 16; ++kt) mbv[kt] = mb[kt*16 + ln16];

    __bf16* __restrict__ Pww = &Pw[w][0];
    const floatx4 z4 = {0.f, 0.f, 0.f, 0.f};
    _Float16* __restrict__ ogb = ogh + ((size_t)h * 256 + i) * 8192;

    #pragma unroll 1
    for (int jt = 0; jt < 4; ++jt) {
        const int jrow0 = w*64 + jt*16;
        const bf16x8 Qf = *(const bf16x8*)&qb[(jrow0 + ln16)*32 + quad*8];

        // ---- scores: 16 MFMAs over all 256 keys ----
        floatx4 S[16];
        #pragma unroll
        for (int kt = 0; kt < 16; ++kt) {
            const bf16x8 Kf = *(const bf16x8*)&Ks[(kt*16 + ln16)*40 + quad*8];
            S[kt] = mfma16(Qf, Kf, z4);
        }

        // ---- bias: mask + tri-bias ----
        #pragma unroll 1
        for (int kg = 0; kg < 4; ++kg) {
            float tbv[16];
            #pragma unroll
            for (int kk = 0; kk < 4; ++kk)
                #pragma unroll
                for (int r = 0; r < 4; ++r)
                    tbv[kk*4+r] = tbh[(size_t)(jrow0 + quad*4 + r) * N + (kg*4+kk)*16 + ln16];
            #pragma unroll
            for (int kk = 0; kk < 4; ++kk)
                #pragma unroll
                for (int r = 0; r < 4; ++r)
                    S[kg*4+kk][r] += mbv[kg*4+kk] + tbv[kk*4+r];
        }

        // ---- full-row softmax (16-lane shfl reduce) ----
        float mrow[4], l[4];
        #pragma unroll
        for (int r = 0; r < 4; ++r) {
            float mx = S[0][r];
            #pragma unroll
            for (int kt = 1; kt < 16; ++kt) mx = fmaxf(mx, S[kt][r]);
            #pragma unroll
            for (int off = 1; off < 16; off <<= 1) mx = fmaxf(mx, __shfl_xor(mx, off));
            mrow[r] = mx; l[r] = 0.f;
        }
        #pragma unroll
        for (int kt = 0; kt < 16; ++kt)
            #pragma unroll
            for (int r = 0; r < 4; ++r) {
                const float p = __expf(S[kt][r] - mrow[r]);
                S[kt][r] = p; l[r] += p;
            }
        #pragma unroll
        for (int r = 0; r < 4; ++r)
            #pragma unroll
            for (int off = 1; off < 16; off <<= 1) l[r] += __shfl_xor(l[r], off);

        // ---- P -> LDS, then PV MFMAs ----
        #pragma unroll
        for (int kt = 0; kt < 16; ++kt)
            #pragma unroll
            for (int r = 0; r < 4; ++r)
                Pww[(quad*4 + r)*264 + kt*16 + ln16] = (__bf16)S[kt][r];

        floatx4 O0 = z4, O1 = z4;
        #pragma unroll
        for (int ks = 0; ks < 8; ++ks) {
            const bf16x8 Af = *(const bf16x8*)&Pww[ln16*264 + ks*32 + quad*8];
            const bf16x8 V0 = *(const bf16x8*)&VT[ln16*264 + ks*32 + quad*8];
            const bf16x8 V1 = *(const bf16x8*)&VT[(16 + ln16)*264 + ks*32 + quad*8];
            O0 = mfma16(Af, V0, O0);
            O1 = mfma16(Af, V1, O1);
        }

        // ---- normalize+gate -> fp16 repack in wave-private LDS ----
        _Float16* Po = (_Float16*)Pww;
        #pragma unroll
        for (int r = 0; r < 4; ++r) {
            const float inv = 1.0f / l[r];
            const int jrow = jrow0 + quad*4 + r;
            const float g0 = (float)gb[jrow*32 + ln16];
            const float g1 = (float)gb[jrow*32 + 16 + ln16];
            const float gate0 = 1.0f / (1.0f + __expf(-(g0 + bg0)));
            const float gate1 = 1.0f / (1.0f + __expf(-(g1 + bg1)));
            Po[(quad*4 + r)*264 + ln16]      = (_Float16)(O0[r] * inv * gate0);
            Po[(quad*4 + r)*264 + 16 + ln16] = (_Float16)(O1[r] * inv * gate1);
        }
        // contiguous 1KB-per-wave store (in-order DS pipe, wave-private)
        {
            const int rr = lane >> 2, cc = lane & 3;
            const halfx8 ov = *(const halfx8*)&Po[rr*264 + cc*8];
            *(halfx8*)&ogb[(size_t)(jrow0 + rr)*32 + cc*8] = ov;
        }
    }
}

// ---------------------------------------------------------------------------
// K4: output projection as f16 MFMA GEMM: out[(j*256+i)*128 + c] =
// sum_k og[(i*256+j), k] * woh[c, k] + bo[c], k = h*32+d over 4 head-slices.
// No LDS; A from og fp16 (coalesced), B from woh (L2-resident).
// ---------------------------------------------------------------------------
__global__ __launch_bounds__(256, 4) void outproj_kernel(
    const _Float16* __restrict__ og, const _Float16* __restrict__ woh,
    const float* __restrict__ bo, float* __restrict__ out)
{
    const int t = threadIdx.x, w = t >> 6, lane = t & 63;
    const int ln16 = lane & 15, quad = lane >> 4;
    const int wr = w >> 1, wc = w & 1;
    const int m_base = blockIdx.x * 128 + wr * 64;
    const int n_base = wc * 64;

    floatx4 Cf[4][4];
    const floatx4 z4 = {0.f, 0.f, 0.f, 0.f};
    #pragma unroll
    for (int mt = 0; mt < 4; ++mt)
        #pragma unroll
        for (int nt = 0; nt < 4; ++nt) Cf[mt][nt] = z4;

    #pragma unroll
    for (int ks = 0; ks < 4; ++ks) {   // ks = head
        halfx8 Af[4], Bf[4];
        #pragma unroll
        for (int mt = 0; mt < 4; ++mt)
            Af[mt] = *(const halfx8*)&og[(size_t)ks*2097152 + (size_t)(m_base + mt*16 + ln16)*32 + quad*8];
        #pragma unroll
        for (int nt = 0; nt < 4; ++nt)
            Bf[nt] = *(const halfx8*)&woh[(n_base + nt*16 + ln16)*128 + ks*32 + quad*8];
        #pragma unroll
        for (int mt = 0; mt < 4; ++mt)
            #pragma unroll
            for (int nt = 0; nt < 4; ++nt)
                Cf[mt][nt] = mfma16h(Af[mt], Bf[nt], Cf[mt][nt]);
    }

    float bov[4];
    #pragma unroll
    for (int nt = 0; nt < 4; ++nt) bov[nt] = bo[n_base + nt*16 + ln16];

    #pragma unroll
    for (int mt = 0; mt < 4; ++mt)
        #pragma unroll
        for (int r = 0; r < 4; ++r) {
            const int m = m_base + mt*16 + quad*4 + r;
            const size_t orow = (size_t)(m & 255) * 256 + (m >> 8);  // (j,i)
            #pragma unroll
            for (int nt = 0; nt < 4; ++nt)
                out[orow*128 + n_base + nt*16 + ln16] = Cf[mt][nt][r] + bov[nt];
        }
}

// ---------------------------------------------------------------------------
extern "C" void kernel_launch(void* const* d_in, const int* in_sizes, int n_in,
                              void* d_out, int out_size, void* d_ws, size_t ws_size,
                              hipStream_t stream) {
    const float* x     = (const float*)d_in[0];
    const float* mask  = (const float*)d_in[1];
    const float* lnw   = (const float*)d_in[2];
    const float* lnb   = (const float*)d_in[3];
    const float* wbias = (const float*)d_in[4];
    const float* wq    = (const float*)d_in[5];
    const float* wk    = (const float*)d_in[6];
    const float* wv    = (const float*)d_in[7];
    const float* wg    = (const float*)d_in[8];
    const float* bg    = (const float*)d_in[9];
    const float* wo    = (const float*)d_in[10];
    const float* bo    = (const float*)d_in[11];
    float* out = (float*)d_out;

    char* wsb = (char*)d_ws;
    __bf16*    xn   = (__bf16*)   (wsb);              // 16.78 MB
    float*     tbj  = (float*)    (wsb + 16777216);   //  1.05 MB
    __bf16*    wTg  = (__bf16*)   (wsb + 17825792);   //  0.13 MB
    _Float16*  woh  = (_Float16*) (wsb + 17956864);   //  0.03 MB
    __bf16*    qbuf = (__bf16*)   (wsb + 17989632);   // 16.78 MB
    __bf16*    kbuf = (__bf16*)   (wsb + 34766848);   // 16.78 MB
    __bf16*    vbuf = (__bf16*)   (wsb + 51544064);   // 16.78 MB
    __bf16*    gbuf = (__bf16*)   (wsb + 68321280);   // 16.78 MB
    _Float16*  ogh  = (_Float16*) (wsb + 85098496);   // 16.78 MB (total ~102 MB)

    wt_kernel<<<40, 256, 0, stream>>>(wq, wk, wv, wg, wo, wTg, woh);
    ln_kernel<<<16384, 256, 0, stream>>>(x, lnw, lnb, wbias, xn, tbj);
    proj_kernel<<<dim3(512, 4), 256, 0, stream>>>(xn, wTg, qbuf, kbuf, vbuf, gbuf);
    attn_kernel<<<1024, 256, 0, stream>>>(tbj, mask, bg, qbuf, kbuf, vbuf, gbuf, ogh);
    outproj_kernel<<<512, 256, 0, stream>>>(ogh, woh, bo, out);
}